// Round 6
// baseline (1299.932 us; speedup 1.0000x reference)
//
#include <hip/hip_runtime.h>

#define BD 4
#define TD 2048
#define DD 2048
#define DID 4096
#define MD (BD*TD)   // 8192 rows
#define CHK 32       // scan chunks
#define CHL (TD/CHK) // 64 steps/chunk

typedef float f32x4 __attribute__((ext_vector_type(4)));
typedef short s16x8 __attribute__((ext_vector_type(8)));
typedef unsigned short u16;
typedef unsigned short u16x4 __attribute__((ext_vector_type(4)));
typedef unsigned short u16x8 __attribute__((ext_vector_type(8)));

__device__ __forceinline__ float bf2f(u16 u) {
    union { unsigned int i; float f; } v; v.i = ((unsigned int)u) << 16; return v.f;
}
__device__ __forceinline__ u16 f2bf(float f) {
    union { float f; unsigned int i; } v; v.f = f;
    unsigned int r = v.i + 0x7fffu + ((v.i >> 16) & 1u);   // RNE
    return (u16)(r >> 16);
}
__device__ __forceinline__ float sigm(float x) { return 1.f / (1.f + __expf(-x)); }

__device__ __forceinline__ void mfma16(f32x4& acc, s16x8 a, s16x8 b) {
    asm volatile("v_mfma_f32_16x16x32_bf16 %0, %1, %2, %0" : "+v"(acc) : "v"(a), "v"(b));
}

__device__ __forceinline__ void gload16(const u16* g, u16* l) {
    __builtin_amdgcn_global_load_lds((__attribute__((address_space(1))) void*)(g),
                                     (__attribute__((address_space(3))) void*)(l),
                                     16, 0, 0);
}

// NO "memory" clobbers in the hot loop (a memory-clobbered asm may read LDS;
// pending global_load_lds WRITE LDS -> backend would drain vmcnt(0) first).
#define BAR()  __builtin_amdgcn_s_barrier()
#define SB()   __builtin_amdgcn_sched_barrier(0)

// ---------------- fp32 -> bf16 convert (weights) ----------------
__global__ __launch_bounds__(256) void cvt_bf16(const float4* __restrict__ in,
                                                u16x4* __restrict__ out, int n4) {
    int i = blockIdx.x * blockDim.x + threadIdx.x;
    int stride = gridDim.x * blockDim.x;
    for (; i < n4; i += stride) {
        float4 v = in[i];
        u16x4 o = { f2bf(v.x), f2bf(v.y), f2bf(v.z), f2bf(v.w) };
        out[i] = o;
    }
}

// ---------------- RMSNorm: fp32 in -> bf16 out ----------------
__global__ __launch_bounds__(256) void rmsnorm_kernel(const float* __restrict__ x,
                                                      const float* __restrict__ w,
                                                      u16* __restrict__ out) {
    const int row = blockIdx.x;
    const int tid = threadIdx.x;
    const float4* x4 = (const float4*)(x + (size_t)row * DD);
    float4 a = x4[tid * 2], b = x4[tid * 2 + 1];
    float s = a.x*a.x + a.y*a.y + a.z*a.z + a.w*a.w
            + b.x*b.x + b.y*b.y + b.z*b.z + b.w*b.w;
#pragma unroll
    for (int off = 32; off >= 1; off >>= 1) s += __shfl_xor(s, off, 64);
    __shared__ float red[4];
    if ((tid & 63) == 0) red[tid >> 6] = s;
    __syncthreads();
    float tot = red[0] + red[1] + red[2] + red[3];
    float rs = rsqrtf(tot * (1.f / DD) + 1e-6f);
    const float4* w4 = (const float4*)w;
    float4 wa = w4[tid * 2], wb = w4[tid * 2 + 1];
    u16x8 o = { f2bf(a.x*rs*wa.x), f2bf(a.y*rs*wa.y), f2bf(a.z*rs*wa.z), f2bf(a.w*rs*wa.w),
                f2bf(b.x*rs*wb.x), f2bf(b.y*rs*wb.y), f2bf(b.z*rs*wb.z), f2bf(b.w*rs*wb.w) };
    *(u16x8*)(out + (size_t)row * DD + tid * 8) = o;
}

// ================= 256x256 single-barrier-per-K-tile GEMM ==================
// C = A(MxK) * B(NxK)^T. 8 waves (2M x 4N), per-wave 128x64 out. BK=64.
// LDS: 2 parity banks of 4 slots {B0,A1,B1,A0} x 16KB. Tile TC reads parity
// TC&1, stages tile TC+1 into the OPPOSITE parity (no same-slot stage/read
// overlap by construction). One barrier region per K-tile: interleaved
// {reads | stages} up top, 64 MFMA with compiler-counted lgkmcnt underneath
// (reads for later clusters service during earlier clusters' MFMA), then
// vmcnt(0) (own stages issued ~a full tile earlier -> wait ~free) + s_barrier.
// Waves free-run inside the tile -> read-service overlaps MFMA across waves.
template<int EPI>
__global__ __launch_bounds__(512, 2)
void gemm8(const u16* __restrict__ A, const u16* __restrict__ Bw,
           int M, int N, int K,
           const float* __restrict__ bias0, const float* __restrict__ bias1,
           const float* resid, float* outf,
           u16* __restrict__ out0, u16* __restrict__ out1, u16* __restrict__ out2,
           int Dsub) {
    __shared__ __align__(16) u16 sl[65536];   // 128 KiB

    const int tid  = threadIdx.x;
    const int lane = tid & 63;
    const int wave = tid >> 6;
    const int wm = wave >> 2;   // 0..1
    const int wn = wave & 3;    // 0..3

    const int id  = blockIdx.x;
    const int xcd = id & 7;
    const int q   = (id >> 3) & 31;   // slot within XCD's resident set
    const int w   = id >> 8;          // resident wave index
    const int brow = ((xcd << 2) | (q & 3)) << 8;
    const int bcol = ((w << 3) | (q >> 2)) << 8;

    // ---- staging source offsets (inverse-swizzled so LDS reads see XOR layout)
    const int hi3   = (tid >> 3) & 7;
    const int chnk  = (tid & 7) ^ hi3;
    const size_t soff0 = (size_t)(tid >> 3) * K + (chnk << 3);
    const size_t soff1 = soff0 + (size_t)64 * K;
    const u16* baseA0 = A  + (size_t)brow * K;
    const u16* baseA1 = A  + (size_t)(brow + 128) * K;
    const u16* baseB0 = Bw + (size_t)bcol * K;
    const u16* baseB1 = Bw + (size_t)(bcol + 128) * K;
    const int Tl = K >> 6;

    // ---- ds_read address pieces
    const int rb  = (lane & 15) * 128;
    const int hi  = lane >> 4;          // 0..3
    const int lo3 = lane & 7;
    const int ck0 = ((hi) ^ lo3) << 4;
    const int ck1 = ((4 + hi) ^ lo3) << 4;
    const char* Ab = (const char*)sl + (wm ? 16384 : 49152) + rb;   // A1 slot1, A0 slot3
    const char* Bb = (const char*)sl + ((wn >> 1) ? 32768 : 0) + ((wn & 1) ? 8192 : 0) + rb;

#define LD8(P) (*(const s16x8*)(P))
#define STAGE(BASE, TS, SLOT) do {                                          \
        int ts_ = (TS); if (ts_ > Tl - 1) ts_ = Tl - 1;                     \
        const u16* s_ = (BASE) + (size_t)ts_ * 64;                          \
        gload16(s_ + soff0, sl + (SLOT) * 8192 + tid * 8);                  \
        gload16(s_ + soff1, sl + (SLOT) * 8192 + 4096 + tid * 8);           \
    } while (0)

    f32x4 acc[8][4];
#pragma unroll
    for (int i = 0; i < 8; ++i)
#pragma unroll
        for (int j = 0; j < 4; ++j) acc[i][j] = (f32x4){0.f, 0.f, 0.f, 0.f};

    s16x8 aF0[4][2], aF1[4][2], bF0[2][2], bF1[2][2];

    // ---- prologue: stage tile 0 into parity-0 slots; wait; barrier
    STAGE(baseB0, 0, 0); STAGE(baseA1, 0, 1); STAGE(baseB1, 0, 2); STAGE(baseA0, 0, 3);
    SB();
    asm volatile("s_waitcnt vmcnt(0)");
    BAR();
    SB();

// 16-MFMA cluster, k-outer: 8 independent accs between any reuse of one acc.
#define CLUST(AR, BR, AO, BO) do {                                           \
    _Pragma("unroll") for (int kk = 0; kk < 2; ++kk)                         \
    _Pragma("unroll") for (int f = 0; f < 4; ++f)                            \
    _Pragma("unroll") for (int g = 0; g < 2; ++g)                            \
        mfma16(acc[(AO)+f][(BO)+g], AR[f][kk], BR[g][kk]);                   \
} while (0)

#define TILE(TC, PAR) do {                                                   \
    /* reads for cluster 1 first (gates earliest MFMA) */                    \
    _Pragma("unroll") for (int f = 0; f < 4; ++f) {                          \
        aF0[f][0] = LD8(Ab + (PAR)*16384 + f*2048 + ck0);                    \
        aF0[f][1] = LD8(Ab + (PAR)*16384 + f*2048 + ck1); }                  \
    _Pragma("unroll") for (int g = 0; g < 2; ++g) {                          \
        bF0[g][0] = LD8(Bb + (PAR)*16384 + g*2048 + ck0);                    \
        bF0[g][1] = LD8(Bb + (PAR)*16384 + g*2048 + ck1); }                  \
    /* stage-ahead tile TC+1 into opposite parity bank */                    \
    STAGE(baseB0, (TC) + 1, 0 + ((PAR) ^ 4));                                \
    STAGE(baseA1, (TC) + 1, 1 + ((PAR) ^ 4));                                \
    /* remaining reads (service under cluster-1 MFMA via counted lgkm) */    \
    _Pragma("unroll") for (int f = 0; f < 4; ++f) {                          \
        aF1[f][0] = LD8(Ab + (PAR)*16384 + 8192 + f*2048 + ck0);             \
        aF1[f][1] = LD8(Ab + (PAR)*16384 + 8192 + f*2048 + ck1); }           \
    _Pragma("unroll") for (int g = 0; g < 2; ++g) {                          \
        bF1[g][0] = LD8(Bb + (PAR)*16384 + 4096 + g*2048 + ck0);             \
        bF1[g][1] = LD8(Bb + (PAR)*16384 + 4096 + g*2048 + ck1); }           \
    STAGE(baseB1, (TC) + 1, 2 + ((PAR) ^ 4));                                \
    STAGE(baseA0, (TC) + 1, 3 + ((PAR) ^ 4));                                \
    __builtin_amdgcn_s_setprio(1);                                           \
    CLUST(aF0, bF0, 0, 0);                                                   \
    CLUST(aF1, bF0, 4, 0);                                                   \
    CLUST(aF1, bF1, 4, 2);                                                   \
    CLUST(aF0, bF1, 0, 2);                                                   \
    __builtin_amdgcn_s_setprio(0);                                           \
    SB();                                                                    \
    asm volatile("s_waitcnt vmcnt(0)");                                      \
    BAR();                                                                   \
    SB();                                                                    \
} while (0)

    for (int tc = 0; tc < Tl; tc += 2) {
        TILE(tc, 0);
        TILE(tc + 1, 4);
    }

    // MFMA-write -> VALU-read hazard fence
#pragma unroll
    for (int i = 0; i < 8; ++i)
#pragma unroll
        for (int j = 0; j < 4; ++j)
            asm volatile("s_nop 7" : "+v"(acc[i][j]));

    const int fr = lane & 15;
    const int r0 = brow + wm * 128 + hi * 4;
    const int c0 = bcol + wn * 64 + fr;
#pragma unroll
    for (int i = 0; i < 8; ++i) {
#pragma unroll
        for (int j = 0; j < 4; ++j) {
            const int gcol = c0 + j * 16;
#pragma unroll
            for (int e = 0; e < 4; ++e) {
                const int grow = r0 + i * 16 + e;
                float c = acc[i][j][e];
                if (EPI == 0) {
                    if (gcol < Dsub) {
                        out0[(size_t)grow * Dsub + gcol] = f2bf(sigm(c + bias0[gcol]));
                    } else if (gcol < 2 * Dsub) {
                        out1[(size_t)grow * Dsub + (gcol - Dsub)] = f2bf(sigm(c + bias1[gcol - Dsub]));
                    } else {
                        out2[(size_t)grow * Dsub + (gcol - 2 * Dsub)] = f2bf(c);
                    }
                } else if (EPI == 1) {
                    const size_t idx = (size_t)grow * N + gcol;
                    outf[idx] = resid[idx] + c;
                } else {
                    if (gcol < Dsub) {
                        out0[(size_t)grow * Dsub + gcol] = f2bf(c * sigm(c));
                    } else {
                        out1[(size_t)grow * Dsub + (gcol - Dsub)] = f2bf(c);
                    }
                }
            }
        }
    }
#undef TILE
#undef CLUST
#undef STAGE
#undef LD8
}

// ================= chunked RG-LRU scan (3 passes) =================
__global__ __launch_bounds__(256)
void scan_partial(const u16* __restrict__ R, const u16* __restrict__ XP,
                  const float* __restrict__ log_dec, float* __restrict__ carry) {
    const int d = blockIdx.x * 256 + threadIdx.x;
    const int k = blockIdx.y;
    const int b = blockIdx.z;
    float a = sigm(log_dec[d]);
    a = fminf(fmaxf(a, 1e-6f), 1.f - 1e-6f);
    const float sc = sqrtf(fmaxf(1.f - a * a, 0.f));
    float h = 0.f;
    size_t idx = ((size_t)b * TD + (size_t)k * CHL) * DD + d;
#pragma unroll 8
    for (int t = 0; t < CHL; ++t) {
        h = a * h + sc * (bf2f(R[idx]) * bf2f(XP[idx]));
        idx += DD;
    }
    carry[((size_t)b * CHK + k) * DD + d] = h;
}

__global__ __launch_bounds__(256)
void scan_carry(const float* __restrict__ state, const float* __restrict__ log_dec,
                const float* __restrict__ carry, float* __restrict__ carryin,
                float* __restrict__ hfin) {
    const int d = blockIdx.x * 256 + threadIdx.x;
    const int b = blockIdx.y;
    float a = sigm(log_dec[d]);
    a = fminf(fmaxf(a, 1e-6f), 1.f - 1e-6f);
    float aL = a;
#pragma unroll
    for (int i = 0; i < 6; ++i) aL *= aL;   // a^64 == a^CHL
    float h = state[(size_t)b * DD + d];
#pragma unroll
    for (int k = 0; k < CHK; ++k) {
        const size_t ci = ((size_t)b * CHK + k) * DD + d;
        carryin[ci] = h;
        h = aL * h + carry[ci];
    }
    hfin[(size_t)b * DD + d] = h;
}

__global__ __launch_bounds__(256)
void scan_final(const u16* __restrict__ R, const u16* __restrict__ XP,
                const u16* __restrict__ G, const float* __restrict__ log_dec,
                const float* __restrict__ carryin, u16* __restrict__ HSG) {
    const int d = blockIdx.x * 256 + threadIdx.x;
    const int k = blockIdx.y;
    const int b = blockIdx.z;
    float a = sigm(log_dec[d]);
    a = fminf(fmaxf(a, 1e-6f), 1.f - 1e-6f);
    const float sc = sqrtf(fmaxf(1.f - a * a, 0.f));
    float h = carryin[((size_t)b * CHK + k) * DD + d];
    size_t idx = ((size_t)b * TD + (size_t)k * CHL) * DD + d;
#pragma unroll 8
    for (int t = 0; t < CHL; ++t) {
        h = a * h + sc * (bf2f(R[idx]) * bf2f(XP[idx]));
        HSG[idx] = f2bf(h * bf2f(G[idx]));
        idx += DD;
    }
}

// ---------------- act = silu(gate)*up (gate already silu'd; in-place) ----------------
__global__ __launch_bounds__(256) void glu_mul(u16x4* __restrict__ g,
                                               const u16x4* __restrict__ u, int n4) {
    int i = blockIdx.x * blockDim.x + threadIdx.x;
    int stride = gridDim.x * blockDim.x;
    for (; i < n4; i += stride) {
        u16x4 gv = g[i], uv = u[i];
        u16x4 o = { f2bf(bf2f(gv[0]) * bf2f(uv[0])), f2bf(bf2f(gv[1]) * bf2f(uv[1])),
                    f2bf(bf2f(gv[2]) * bf2f(uv[2])), f2bf(bf2f(gv[3]) * bf2f(uv[3])) };
        g[i] = o;
    }
}

extern "C" void kernel_launch(void* const* d_in, const int* in_sizes, int n_in,
                              void* d_out, int out_size, void* d_ws, size_t ws_size,
                              hipStream_t stream) {
    const float* x       = (const float*)d_in[0];
    const float* state   = (const float*)d_in[1];
    const float* w_norm1 = (const float*)d_in[2];
    const float* W_in    = (const float*)d_in[3];
    const float* W_r     = (const float*)d_in[4];
    const float* b_r     = (const float*)d_in[5];
    const float* W_i     = (const float*)d_in[6];
    const float* b_i     = (const float*)d_in[7];
    const float* log_dec = (const float*)d_in[8];
    const float* W_out   = (const float*)d_in[9];
    const float* w_norm2 = (const float*)d_in[10];
    const float* W_gate  = (const float*)d_in[11];
    const float* W_up    = (const float*)d_in[12];
    const float* W_down  = (const float*)d_in[13];

    float* out  = (float*)d_out;
    float* hfin = out + (size_t)MD * DD;

    u16* wstack1 = (u16*)d_ws;                              // [W_r;W_i;W_in] 3*D*D
    u16* wout2   = wstack1 + (size_t)3 * DD * DD;           // W_out D*D
    u16* wstack2 = wout2   + (size_t)DD * DD;               // [W_gate;W_up] 2*DI*D
    u16* wdown2  = wstack2 + (size_t)2 * DID * DD;          // W_down D*DI
    u16* bufN    = wdown2  + (size_t)DD * DID;              // M*D
    u16* bufR    = bufN    + (size_t)MD * DD;               // M*D
    u16* bufG    = bufR    + (size_t)MD * DD;               // M*D
    u16* bufXP   = bufG    + (size_t)MD * DD;               // M*D
    u16* spare   = bufXP   + (size_t)MD * DD;               // M*D spare (up-proj tail)
    float* carry   = (float*)spare;                         // B*CHK*D fp32 (1 MB)
    float* carryin = carry + (size_t)BD * CHK * DD;         // B*CHK*D fp32 (1 MB)

    cvt_bf16<<<1024, 256, 0, stream>>>((const float4*)W_r,   (u16x4*)wstack1,                      DD*DD/4);
    cvt_bf16<<<1024, 256, 0, stream>>>((const float4*)W_i,   (u16x4*)(wstack1 + (size_t)DD*DD),    DD*DD/4);
    cvt_bf16<<<1024, 256, 0, stream>>>((const float4*)W_in,  (u16x4*)(wstack1 + (size_t)2*DD*DD),  DD*DD/4);
    cvt_bf16<<<1024, 256, 0, stream>>>((const float4*)W_out, (u16x4*)wout2,                        DD*DD/4);
    cvt_bf16<<<1024, 256, 0, stream>>>((const float4*)W_gate,(u16x4*)wstack2,                      DID*DD/4);
    cvt_bf16<<<1024, 256, 0, stream>>>((const float4*)W_up,  (u16x4*)(wstack2 + (size_t)DID*DD),   DID*DD/4);
    cvt_bf16<<<1024, 256, 0, stream>>>((const float4*)W_down,(u16x4*)wdown2,                       DD*DID/4);

    rmsnorm_kernel<<<MD, 256, 0, stream>>>(x, w_norm1, bufN);

    // r/g/xp projections: M=8192, N=6144, K=2048
    gemm8<0><<<(MD/256) * (3*DD/256), 512, 0, stream>>>(bufN, wstack1, MD, 3*DD, DD,
                                       b_r, b_i, nullptr, nullptr, bufR, bufG, bufXP, DD);

    // chunked RG-LRU scan
    dim3 gp(DD/256, CHK, BD);
    scan_partial<<<gp, 256, 0, stream>>>(bufR, bufXP, log_dec, carry);
    dim3 gc(DD/256, BD);
    scan_carry<<<gc, 256, 0, stream>>>(state, log_dec, carry, carryin, hfin);
    scan_final<<<gp, 256, 0, stream>>>(bufR, bufXP, bufG, log_dec, carryin, bufN);

    // x2 = x + hsg @ W_out^T
    gemm8<1><<<(MD/256) * (DD/256), 512, 0, stream>>>(bufN, wout2, MD, DD, DD,
                                       nullptr, nullptr, x, out, nullptr, nullptr, nullptr, 0);

    rmsnorm_kernel<<<MD, 256, 0, stream>>>(out, w_norm2, bufN);

    // gate/up projections: N=8192
    gemm8<2><<<(MD/256) * (2*DID/256), 512, 0, stream>>>(bufN, wstack2, MD, 2*DID, DD,
                                       nullptr, nullptr, nullptr, nullptr, bufR, bufXP, nullptr, DID);

    glu_mul<<<2048, 256, 0, stream>>>((u16x4*)bufR, (const u16x4*)bufXP, MD * DID / 4);

    // out = x2 + act @ W_down^T
    gemm8<1><<<(MD/256) * (DD/256), 512, 0, stream>>>(bufR, wdown2, MD, DD, DID,
                                       nullptr, nullptr, out, out, nullptr, nullptr, nullptr, 0);
}

// Round 8
// 919.853 us; speedup vs baseline: 1.4132x; 1.4132x over previous
//
#include <hip/hip_runtime.h>

#define BD 4
#define TD 2048
#define DD 2048
#define DID 4096
#define MD (BD*TD)   // 8192 rows
#define CHK 32       // scan chunks
#define CHL (TD/CHK) // 64 steps/chunk

typedef float f32x4 __attribute__((ext_vector_type(4)));
typedef short s16x8 __attribute__((ext_vector_type(8)));
typedef unsigned short u16;
typedef unsigned short u16x4 __attribute__((ext_vector_type(4)));
typedef unsigned short u16x8 __attribute__((ext_vector_type(8)));

__device__ __forceinline__ float bf2f(u16 u) {
    union { unsigned int i; float f; } v; v.i = ((unsigned int)u) << 16; return v.f;
}
__device__ __forceinline__ u16 f2bf(float f) {
    union { float f; unsigned int i; } v; v.f = f;
    unsigned int r = v.i + 0x7fffu + ((v.i >> 16) & 1u);   // RNE
    return (u16)(r >> 16);
}
__device__ __forceinline__ float sigm(float x) { return 1.f / (1.f + __expf(-x)); }

// Non-volatile register-only MFMA: ordering w.r.t. memory is provided entirely
// by __syncthreads() fences; compiler may interleave MFMA with ds_reads under
// its own counted lgkmcnt (the m97 mechanism).
__device__ __forceinline__ void mfma16(f32x4& acc, s16x8 a, s16x8 b) {
    asm("v_mfma_f32_16x16x32_bf16 %0, %1, %2, %0" : "+v"(acc) : "v"(a), "v"(b));
}

__device__ __forceinline__ void gload16(const u16* g, u16* l) {
    __builtin_amdgcn_global_load_lds((__attribute__((address_space(1))) void*)(g),
                                     (__attribute__((address_space(3))) void*)(l),
                                     16, 0, 0);
}

// ---------------- fused fp32 -> bf16 weight convert (7 segments) ----------------
// dst segments are contiguous in ws: [W_r,W_i,W_in,W_out] 1M float4 each, then
// [W_gate,W_up,W_down] 2M float4 each. Total 10M float4.
__global__ __launch_bounds__(256)
void cvt_all(const float4* __restrict__ s0, const float4* __restrict__ s1,
             const float4* __restrict__ s2, const float4* __restrict__ s3,
             const float4* __restrict__ s4, const float4* __restrict__ s5,
             const float4* __restrict__ s6, u16x4* __restrict__ dst, int n4) {
    const int SEG = DD * DD / 4;   // 1048576
    int i = blockIdx.x * blockDim.x + threadIdx.x;
    int stride = gridDim.x * blockDim.x;
    for (; i < n4; i += stride) {
        const float4* s; int off;
        if (i < 4 * SEG) {
            int k = i / SEG;
            s = (k == 0) ? s0 : (k == 1) ? s1 : (k == 2) ? s2 : s3;
            off = i - k * SEG;
        } else {
            int j = i - 4 * SEG;
            int k = j / (2 * SEG);
            s = (k == 0) ? s4 : (k == 1) ? s5 : s6;
            off = j - k * 2 * SEG;
        }
        float4 v = s[off];
        u16x4 o = { f2bf(v.x), f2bf(v.y), f2bf(v.z), f2bf(v.w) };
        dst[i] = o;
    }
}

// ---------------- RMSNorm: fp32 in -> bf16 out ----------------
__global__ __launch_bounds__(256) void rmsnorm_kernel(const float* __restrict__ x,
                                                      const float* __restrict__ w,
                                                      u16* __restrict__ out) {
    const int row = blockIdx.x;
    const int tid = threadIdx.x;
    const float4* x4 = (const float4*)(x + (size_t)row * DD);
    float4 a = x4[tid * 2], b = x4[tid * 2 + 1];
    float s = a.x*a.x + a.y*a.y + a.z*a.z + a.w*a.w
            + b.x*b.x + b.y*b.y + b.z*b.z + b.w*b.w;
#pragma unroll
    for (int off = 32; off >= 1; off >>= 1) s += __shfl_xor(s, off, 64);
    __shared__ float red[4];
    if ((tid & 63) == 0) red[tid >> 6] = s;
    __syncthreads();
    float tot = red[0] + red[1] + red[2] + red[3];
    float rs = rsqrtf(tot * (1.f / DD) + 1e-6f);
    const float4* w4 = (const float4*)w;
    float4 wa = w4[tid * 2], wb = w4[tid * 2 + 1];
    u16x8 o = { f2bf(a.x*rs*wa.x), f2bf(a.y*rs*wa.y), f2bf(a.z*rs*wa.z), f2bf(a.w*rs*wa.w),
                f2bf(b.x*rs*wb.x), f2bf(b.y*rs*wb.y), f2bf(b.z*rs*wb.z), f2bf(b.w*rs*wb.w) };
    *(u16x8*)(out + (size_t)row * DD + tid * 8) = o;
}

// ============ 128x128 tile GEMM, BK=64, C = A(MxK) * B(NxK)^T ============
// 4 waves (2x2 of 64x64). Single-buffered LDS (2 x 16 KB), __syncthreads
// ordering (compiler-managed waits — proven-correct m97 structure).
// LDS rows are XOR-swizzled: LDS[row][chunk c] holds global chunk c^(row&7)
// (16B chunks, 8/row); achieved by pre-swizzling the gload SOURCE address
// (dest stays linear, as global_load_lds requires). ds_reads apply the same
// XOR -> conflict-free (uniform 2 lanes/bank footprint).
// EPI 0: split-N {r=sigmoid(+b_r), g=sigmoid(+b_i), xp}  EPI 1: outf=resid+c
// EPI 2: split-N {silu(gate), up}
template<int EPI>
__global__ __launch_bounds__(256)
void gemm_bt(const u16* __restrict__ A, const u16* __restrict__ Bw,
             int M, int N, int K,
             const float* __restrict__ bias0, const float* __restrict__ bias1,
             const float* resid, float* outf,
             u16* __restrict__ out0, u16* __restrict__ out1, u16* __restrict__ out2,
             int Dsub) {
    __shared__ __align__(16) u16 lA[128 * 64];   // 16 KB
    __shared__ __align__(16) u16 lB[128 * 64];   // 16 KB
    const int tid  = threadIdx.x;
    const int lane = tid & 63;
    const int wave = tid >> 6;
    const int wr = (wave >> 1) << 6;
    const int wc = (wave & 1) << 6;
    const int brow = blockIdx.x * 128;
    const int bcol = blockIdx.y * 128;

    // staging: 32 rows/issue, 8 chunks/row; source chunk pre-swizzled
    const int srow  = tid >> 3;                    // 0..31
    const int schnk = (tid & 7) ^ (srow & 7);      // inverse-swizzle source
    const size_t soff = (size_t)srow * K + (schnk << 3);
    const u16* gA = A  + (size_t)brow * K + soff;
    const u16* gB = Bw + (size_t)bcol * K + soff;
    u16* lAp = lA + tid * 8;                       // linear dest, lane*16B
    u16* lBp = lB + tid * 8;

    // read-address pieces
    const int fr = lane & 15;
    const int lg = lane >> 4;                      // 0..3
    const int ck0 = ((lg)     ^ (fr & 7)) << 4;    // k-half 0 chunk byte
    const int ck1 = ((4 + lg) ^ (fr & 7)) << 4;    // k-half 1 chunk byte
    const char* lAc = (const char*)lA;
    const char* lBc = (const char*)lB;

    f32x4 acc[4][4];
#pragma unroll
    for (int i = 0; i < 4; ++i)
#pragma unroll
        for (int j = 0; j < 4; ++j)
            acc[i][j] = (f32x4){0.f, 0.f, 0.f, 0.f};

    for (int k0 = 0; k0 < K; k0 += 64) {
#pragma unroll
        for (int s = 0; s < 4; ++s) {
            gload16(gA + k0 + (size_t)s * 32 * K, lAp + s * 2048);
            gload16(gB + k0 + (size_t)s * 32 * K, lBp + s * 2048);
        }
        __syncthreads();
        s16x8 af[4][2], bq[4][2];
#pragma unroll
        for (int i = 0; i < 4; ++i) {
            const int ra = (wr + i * 16 + fr) * 128;
            const int rb = (wc + i * 16 + fr) * 128;
            af[i][0] = *(const s16x8*)(lAc + ra + ck0);
            af[i][1] = *(const s16x8*)(lAc + ra + ck1);
            bq[i][0] = *(const s16x8*)(lBc + rb + ck0);
            bq[i][1] = *(const s16x8*)(lBc + rb + ck1);
        }
#pragma unroll
        for (int h = 0; h < 2; ++h)
#pragma unroll
            for (int i = 0; i < 4; ++i)
#pragma unroll
                for (int j = 0; j < 4; ++j)
                    mfma16(acc[i][j], af[i][h], bq[j][h]);
        __syncthreads();
    }

    // MFMA-write -> VALU-read hazard fence
#pragma unroll
    for (int i = 0; i < 4; ++i)
#pragma unroll
        for (int j = 0; j < 4; ++j)
            asm volatile("s_nop 7" : "+v"(acc[i][j]));

    const int r0 = brow + wr + (lg << 2);
    const int c0 = bcol + wc + fr;
#pragma unroll
    for (int i = 0; i < 4; ++i) {
#pragma unroll
        for (int j = 0; j < 4; ++j) {
            const int gcol = c0 + j * 16;
#pragma unroll
            for (int e = 0; e < 4; ++e) {
                const int grow = r0 + i * 16 + e;
                float c = acc[i][j][e];
                if (EPI == 0) {
                    if (gcol < Dsub) {
                        out0[(size_t)grow * Dsub + gcol] = f2bf(sigm(c + bias0[gcol]));
                    } else if (gcol < 2 * Dsub) {
                        out1[(size_t)grow * Dsub + (gcol - Dsub)] = f2bf(sigm(c + bias1[gcol - Dsub]));
                    } else {
                        out2[(size_t)grow * Dsub + (gcol - 2 * Dsub)] = f2bf(c);
                    }
                } else if (EPI == 1) {
                    const size_t idx = (size_t)grow * N + gcol;
                    outf[idx] = resid[idx] + c;
                } else {
                    if (gcol < Dsub) {
                        out0[(size_t)grow * Dsub + gcol] = f2bf(c * sigm(c));
                    } else {
                        out1[(size_t)grow * Dsub + (gcol - Dsub)] = f2bf(c);
                    }
                }
            }
        }
    }
}

// ================= chunked RG-LRU scan (3 passes) =================
__global__ __launch_bounds__(256)
void scan_partial(const u16* __restrict__ R, const u16* __restrict__ XP,
                  const float* __restrict__ log_dec, float* __restrict__ carry) {
    const int d = blockIdx.x * 256 + threadIdx.x;
    const int k = blockIdx.y;
    const int b = blockIdx.z;
    float a = sigm(log_dec[d]);
    a = fminf(fmaxf(a, 1e-6f), 1.f - 1e-6f);
    const float sc = sqrtf(fmaxf(1.f - a * a, 0.f));
    float h = 0.f;
    size_t idx = ((size_t)b * TD + (size_t)k * CHL) * DD + d;
#pragma unroll 8
    for (int t = 0; t < CHL; ++t) {
        h = a * h + sc * (bf2f(R[idx]) * bf2f(XP[idx]));
        idx += DD;
    }
    carry[((size_t)b * CHK + k) * DD + d] = h;
}

__global__ __launch_bounds__(256)
void scan_carry(const float* __restrict__ state, const float* __restrict__ log_dec,
                const float* __restrict__ carry, float* __restrict__ carryin,
                float* __restrict__ hfin) {
    const int d = blockIdx.x * 256 + threadIdx.x;
    const int b = blockIdx.y;
    float a = sigm(log_dec[d]);
    a = fminf(fmaxf(a, 1e-6f), 1.f - 1e-6f);
    float aL = a;
#pragma unroll
    for (int i = 0; i < 6; ++i) aL *= aL;   // a^64 == a^CHL
    float h = state[(size_t)b * DD + d];
#pragma unroll
    for (int k = 0; k < CHK; ++k) {
        const size_t ci = ((size_t)b * CHK + k) * DD + d;
        carryin[ci] = h;
        h = aL * h + carry[ci];
    }
    hfin[(size_t)b * DD + d] = h;
}

__global__ __launch_bounds__(256)
void scan_final(const u16* __restrict__ R, const u16* __restrict__ XP,
                const u16* __restrict__ G, const float* __restrict__ log_dec,
                const float* __restrict__ carryin, u16* __restrict__ HSG) {
    const int d = blockIdx.x * 256 + threadIdx.x;
    const int k = blockIdx.y;
    const int b = blockIdx.z;
    float a = sigm(log_dec[d]);
    a = fminf(fmaxf(a, 1e-6f), 1.f - 1e-6f);
    const float sc = sqrtf(fmaxf(1.f - a * a, 0.f));
    float h = carryin[((size_t)b * CHK + k) * DD + d];
    size_t idx = ((size_t)b * TD + (size_t)k * CHL) * DD + d;
#pragma unroll 8
    for (int t = 0; t < CHL; ++t) {
        h = a * h + sc * (bf2f(R[idx]) * bf2f(XP[idx]));
        HSG[idx] = f2bf(h * bf2f(G[idx]));
        idx += DD;
    }
}

// ---------------- act = silu(gate)*up (gate already silu'd; in-place) ----------------
__global__ __launch_bounds__(256) void glu_mul(u16x4* __restrict__ g,
                                               const u16x4* __restrict__ u, int n4) {
    int i = blockIdx.x * blockDim.x + threadIdx.x;
    int stride = gridDim.x * blockDim.x;
    for (; i < n4; i += stride) {
        u16x4 gv = g[i], uv = u[i];
        u16x4 o = { f2bf(bf2f(gv[0]) * bf2f(uv[0])), f2bf(bf2f(gv[1]) * bf2f(uv[1])),
                    f2bf(bf2f(gv[2]) * bf2f(uv[2])), f2bf(bf2f(gv[3]) * bf2f(uv[3])) };
        g[i] = o;
    }
}

extern "C" void kernel_launch(void* const* d_in, const int* in_sizes, int n_in,
                              void* d_out, int out_size, void* d_ws, size_t ws_size,
                              hipStream_t stream) {
    const float* x       = (const float*)d_in[0];
    const float* state   = (const float*)d_in[1];
    const float* w_norm1 = (const float*)d_in[2];
    const float* W_in    = (const float*)d_in[3];
    const float* W_r     = (const float*)d_in[4];
    const float* b_r     = (const float*)d_in[5];
    const float* W_i     = (const float*)d_in[6];
    const float* b_i     = (const float*)d_in[7];
    const float* log_dec = (const float*)d_in[8];
    const float* W_out   = (const float*)d_in[9];
    const float* w_norm2 = (const float*)d_in[10];
    const float* W_gate  = (const float*)d_in[11];
    const float* W_up    = (const float*)d_in[12];
    const float* W_down  = (const float*)d_in[13];

    float* out  = (float*)d_out;
    float* hfin = out + (size_t)MD * DD;

    u16* wstack1 = (u16*)d_ws;                              // [W_r;W_i;W_in] 3*D*D
    u16* wout2   = wstack1 + (size_t)3 * DD * DD;           // W_out D*D
    u16* wstack2 = wout2   + (size_t)DD * DD;               // [W_gate;W_up] 2*DI*D
    u16* wdown2  = wstack2 + (size_t)2 * DID * DD;          // W_down D*DI
    u16* bufN    = wdown2  + (size_t)DD * DID;              // M*D
    u16* bufR    = bufN    + (size_t)MD * DD;               // M*D
    u16* bufG    = bufR    + (size_t)MD * DD;               // M*D
    u16* bufXP   = bufG    + (size_t)MD * DD;               // M*D
    u16* spare   = bufXP   + (size_t)MD * DD;               // M*D spare (up-proj tail)
    float* carry   = (float*)spare;                         // B*CHK*D fp32 (1 MB)
    float* carryin = carry + (size_t)BD * CHK * DD;         // B*CHK*D fp32 (1 MB)

    // 1) fused weight converts (dst contiguous: wstack1..wdown2 = 40M u16)
    cvt_all<<<2048, 256, 0, stream>>>((const float4*)W_r, (const float4*)W_i,
                                      (const float4*)W_in, (const float4*)W_out,
                                      (const float4*)W_gate, (const float4*)W_up,
                                      (const float4*)W_down, (u16x4*)wstack1,
                                      (3*DD*DD + DD*DD + 2*DID*DD + DD*DID) / 4);

    rmsnorm_kernel<<<MD, 256, 0, stream>>>(x, w_norm1, bufN);

    // r/g/xp projections: M=8192, N=6144, K=2048
    {
        dim3 g1(MD / 128, (3 * DD) / 128);
        gemm_bt<0><<<g1, 256, 0, stream>>>(bufN, wstack1, MD, 3 * DD, DD,
                                           b_r, b_i, nullptr, nullptr, bufR, bufG, bufXP, DD);
    }

    // chunked RG-LRU scan
    {
        dim3 gp(DD / 256, CHK, BD);
        scan_partial<<<gp, 256, 0, stream>>>(bufR, bufXP, log_dec, carry);
        dim3 gc(DD / 256, BD);
        scan_carry<<<gc, 256, 0, stream>>>(state, log_dec, carry, carryin, hfin);
        scan_final<<<gp, 256, 0, stream>>>(bufR, bufXP, bufG, log_dec, carryin, bufN);
    }

    // x2 = x + hsg @ W_out^T
    {
        dim3 g2(MD / 128, DD / 128);
        gemm_bt<1><<<g2, 256, 0, stream>>>(bufN, wout2, MD, DD, DD,
                                           nullptr, nullptr, x, out, nullptr, nullptr, nullptr, 0);
    }

    rmsnorm_kernel<<<MD, 256, 0, stream>>>(out, w_norm2, bufN);

    // gate/up projections: N=8192
    {
        dim3 g3(MD / 128, (2 * DID) / 128);
        gemm_bt<2><<<g3, 256, 0, stream>>>(bufN, wstack2, MD, 2 * DID, DD,
                                           nullptr, nullptr, nullptr, nullptr, bufR, bufXP, nullptr, DID);
    }

    glu_mul<<<2048, 256, 0, stream>>>((u16x4*)bufR, (const u16x4*)bufXP, MD * DID / 4);

    // out = x2 + act @ W_down^T
    {
        dim3 g4(MD / 128, DD / 128);
        gemm_bt<1><<<g4, 256, 0, stream>>>(bufR, wdown2, MD, DD, DID,
                                           nullptr, nullptr, out, out, nullptr, nullptr, nullptr, 0);
    }
}